// Round 13
// baseline (203.749 us; speedup 1.0000x reference)
//
#include <hip/hip_runtime.h>
#include <math.h>

#define EPS 1e-8f
constexpr int D     = 1024;
constexpr int NEMB  = 80;
constexpr int K     = 1849;
constexpr int BATCH = 4;
constexpr int P     = 43;
constexpr int TGT   = 602;
constexpr int ROWS  = BATCH * K;                   // 7396
constexpr size_t PLANE = (size_t)BATCH * NEMB * K; // 591,680
constexpr int SPLIT = 8;
constexpr int KC    = D / SPLIT;                   // 128

typedef float nfloat4 __attribute__((ext_vector_type(4)));

// ---------------- bicubic tap weights (exact fp64, matches numpy) -----------
__device__ inline double cubic_w(double x) {
  const double A = -0.75;
  x = fabs(x);
  if (x <= 1.0) return ((A + 2.0) * x - (A + 3.0)) * x * x + 1.0;
  if (x < 2.0)  return A * (((x - 5.0) * x + 8.0) * x - 4.0);
  return 0.0;
}

__device__ inline float block_reduce_sum256(float v) {
  #pragma unroll
  for (int off = 32; off > 0; off >>= 1) v += __shfl_down(v, off, 64);
  __shared__ float red[4];
  int lane = threadIdx.x & 63, wid = threadIdx.x >> 6;
  if (lane == 0) red[wid] = v;
  __syncthreads();
  float r = 0.f;
  if (threadIdx.x == 0) r = red[0] + red[1] + red[2] + red[3];
  return r;
}

// blocks 0..79: e_norm rows; block 80: the 14-entry periodic weight table.
__global__ __launch_bounds__(256) void prep_kernel(
    const float* __restrict__ emb, float* __restrict__ e_norm,
    float4* __restrict__ gtw) {
  int bid = blockIdx.x;
  if (bid < NEMB) {
    float4 v = ((const float4*)(emb + (size_t)bid * D))[threadIdx.x];
    float s = v.x * v.x + v.y * v.y + v.z * v.z + v.w * v.w;
    s = block_reduce_sum256(s);
    if (threadIdx.x == 0) e_norm[bid] = sqrtf(s);
  } else {
    int j = threadIdx.x;
    if (j < 14) {
      double scale = (double)P / (double)TGT;
      double src = ((double)j + 0.5) * scale - 0.5;
      double fb = floor(src);
      double t = src - fb;
      float4 w;
      w.x = (float)cubic_w(t + 1.0);
      w.y = (float)cubic_w(t);
      w.z = (float)cubic_w(t - 1.0);
      w.w = (float)cubic_w(t - 2.0);
      gtw[j] = w;
    }
  }
}

// -------- split-K GEMM, 2-phase pipelined (R6 verbatim, SPLIT=8) -------------
constexpr int BM  = 64;
constexpr int BK  = 32;
constexpr int LDA = 36; // padded LDS row stride (floats), 16B aligned
constexpr int NT  = KC / BK; // 4 K-tiles per block

__device__ inline float dot4(float4 v) {
  return v.x * v.x + v.y * v.y + v.z * v.z + v.w * v.w;
}

__global__ __launch_bounds__(256) void gemm_partial(
    const float* __restrict__ feats, const float* __restrict__ emb,
    float* __restrict__ part, float* __restrict__ fpart) {
  __shared__ float As[BM * LDA];
  __shared__ float Bs[NEMB * LDA];
  int t = threadIdx.x;
  int row0 = blockIdx.x * BM;
  int s = blockIdx.y;
  int tr = t >> 4, tc = t & 15;
  float acc[4][5] = {{0.f}};
  float ssq0 = 0.f, ssq1 = 0.f;

  int r = t >> 3, dg = t & 7;
  int gr0 = row0 + r, gr1 = row0 + 32 + r;
  bool ok0 = gr0 < ROWS, ok1 = gr1 < ROWS;
  const float* pA0 = feats + (size_t)gr0 * D + dg * 4;
  const float* pA1 = feats + (size_t)gr1 * D + dg * 4;
  const float* pB0 = emb + (size_t)r * D + dg * 4;
  const float* pB1 = emb + (size_t)(32 + r) * D + dg * 4;
  const float* pB2 = emb + (size_t)(64 + r) * D + dg * 4;
  bool okB2 = t < 128;

  int kbeg = s * KC;
  const float4 zero = make_float4(0.f, 0.f, 0.f, 0.f);
  float4 a0 = ok0 ? *(const float4*)(pA0 + kbeg) : zero;
  float4 a1 = ok1 ? *(const float4*)(pA1 + kbeg) : zero;
  float4 b0 = *(const float4*)(pB0 + kbeg);
  float4 b1 = *(const float4*)(pB1 + kbeg);
  float4 b2 = okB2 ? *(const float4*)(pB2 + kbeg) : zero;

  for (int tile = 0; tile < NT; ++tile) {
    ssq0 += dot4(a0);
    *(float4*)(As + r * LDA + dg * 4) = a0;
    ssq1 += dot4(a1);
    *(float4*)(As + (32 + r) * LDA + dg * 4) = a1;
    *(float4*)(Bs + r * LDA + dg * 4) = b0;
    *(float4*)(Bs + (32 + r) * LDA + dg * 4) = b1;
    if (okB2) *(float4*)(Bs + (64 + r) * LDA + dg * 4) = b2;
    __syncthreads();

    if (tile + 1 < NT) {
      int k1 = kbeg + (tile + 1) * BK;
      a0 = ok0 ? *(const float4*)(pA0 + k1) : zero;
      a1 = ok1 ? *(const float4*)(pA1 + k1) : zero;
      b0 = *(const float4*)(pB0 + k1);
      b1 = *(const float4*)(pB1 + k1);
      if (okB2) b2 = *(const float4*)(pB2 + k1);
    }

    #pragma unroll
    for (int dd = 0; dd < BK; dd += 4) {
      float4 a[4], b[5];
      #pragma unroll
      for (int j = 0; j < 4; ++j)  a[j]  = *(const float4*)(As + (tr * 4 + j) * LDA + dd);
      #pragma unroll
      for (int i2 = 0; i2 < 5; ++i2) b[i2] = *(const float4*)(Bs + (tc + i2 * 16) * LDA + dd);
      #pragma unroll
      for (int j = 0; j < 4; ++j)
        #pragma unroll
        for (int i2 = 0; i2 < 5; ++i2)
          acc[j][i2] += a[j].x * b[i2].x + a[j].y * b[i2].y +
                        a[j].z * b[i2].z + a[j].w * b[i2].w;
    }
    __syncthreads();
  }

  #pragma unroll
  for (int off = 4; off > 0; off >>= 1) {
    ssq0 += __shfl_down(ssq0, off, 8);
    ssq1 += __shfl_down(ssq1, off, 8);
  }
  if ((t & 7) == 0) {
    if (gr0 < ROWS) fpart[(size_t)s * ROWS + gr0] = ssq0;
    if (gr1 < ROWS) fpart[(size_t)s * ROWS + gr1] = ssq1;
  }

  float* pplane = part + (size_t)s * PLANE;
  #pragma unroll
  for (int j = 0; j < 4; ++j) {
    int gr = row0 + tr * 4 + j;
    if (gr >= ROWS) continue;
    int b_ = gr / K;
    int k  = gr - b_ * K;
    #pragma unroll
    for (int i2 = 0; i2 < 5; ++i2) {
      int n = tc + i2 * 16;
      pplane[((size_t)(b_ * NEMB + n)) * K + k] = acc[j][i2];
    }
  }
}

// -------- reduce partials -> cosim (R6 verbatim, SPLIT=8) --------------------
__global__ __launch_bounds__(256) void reduce_kernel(
    const float* __restrict__ part, const float* __restrict__ fpart,
    const float* __restrict__ e_norm, float* __restrict__ cosim) {
  size_t e = (size_t)blockIdx.x * 256 + threadIdx.x;
  if (e >= PLANE) return;
  int bn = (int)(e / K);
  int k  = (int)(e - (size_t)bn * K);
  int b_ = bn / NEMB;
  int n  = bn - b_ * NEMB;
  int gr = b_ * K + k;
  float dot = 0.f, fn2 = 0.f;
  #pragma unroll
  for (int s = 0; s < SPLIT; ++s) {
    dot += part[(size_t)s * PLANE + e];
    fn2 += fpart[(size_t)s * ROWS + gr];
  }
  cosim[e] = dot / (sqrtf(fn2) * e_norm[n] + EPS);
}

// ---------------- separable bicubic resize: float4-NT direct -----------------
// grid (43, 320), 192 threads. Threads 0..149 own 4 output columns each
// (ta[6][5] covers the odd-row 2-column shift that keeps 16B store alignment:
// row start offsets alternate 0/2 mod 4 floats since 602%4=2, 602^2%4=0).
// Even rows: quad at W=4t; odd rows: quad at W=4t+2. Tail threads 150/151
// cover (600,601) on even rows / (0,1) on odd rows with plain float2.
// 16B NT stores ONLY (8B NT is broken on gfx950 per R9-R12 bisection).
__global__ __launch_bounds__(192) void resize_kernel(
    const float* __restrict__ cosim, const float4* __restrict__ gtw,
    float* __restrict__ out) {
  __shared__ float img[5 * P];
  __shared__ float4 wq[14];

  int bn = blockIdx.y;
  int c  = blockIdx.x;
  int t  = threadIdx.x;

  int hmin = max(0, c - 2), hmax = min(P - 1, c + 2);
  int NH = hmax - hmin + 1;

  if (t < 14) wq[t] = gtw[t];
  const float* src = cosim + (size_t)bn * (P * P) + hmin * P;
  for (int i = t; i < NH * P; i += 192) img[i] = src[i];
  __syncthreads();

  float* obase = out + (size_t)bn * TGT * TGT + (size_t)(c * 14) * TGT;

  if (t < 150) {
    int W0 = t * 4;
    int m0 = W0 / 14;
    int j0 = W0 - m0 * 14;
    int base0 = m0 - 2 + (j0 >= 7);

    int s[6]; float4 w[6];
    #pragma unroll
    for (int i = 0; i < 6; ++i) {
      int jj = j0 + i, mm = m0;
      if (jj >= 14) { jj -= 14; mm += 1; }
      w[i] = wq[jj];
      s[i] = (mm - 2 + (jj >= 7)) - base0;   // 0 or 1 (at most one 6->7 crossing)
    }
    int ii[5];
    #pragma unroll
    for (int k = 0; k < 5; ++k) ii[k] = min(P - 1, max(0, base0 + k));

    float ta[6][5];
    #pragma unroll
    for (int h = 0; h < 5; ++h) {
      const float* rowp = img + h * P;
      float v0 = rowp[ii[0]], v1 = rowp[ii[1]], v2 = rowp[ii[2]],
            v3 = rowp[ii[3]], v4 = rowp[ii[4]];
      #pragma unroll
      for (int i = 0; i < 6; ++i) {
        float u0 = s[i] ? v1 : v0;
        float u1 = s[i] ? v2 : v1;
        float u2 = s[i] ? v3 : v2;
        float u3 = s[i] ? v4 : v3;
        ta[i][h] = w[i].x * u0 + w[i].y * u1 + w[i].z * u2 + w[i].w * u3;
      }
    }

    #define VROWS(R0, a0, a1, a2, a3)                                          \
      _Pragma("unroll")                                                        \
      for (int r = R0; r < R0 + 7; ++r) {                                      \
        float4 hw = wq[r];                                                     \
        const int co = (r & 1) ? 2 : 0;                                        \
        nfloat4 o;                                                             \
        o.x = hw.x*ta[co+0][a0] + hw.y*ta[co+0][a1] + hw.z*ta[co+0][a2] + hw.w*ta[co+0][a3]; \
        o.y = hw.x*ta[co+1][a0] + hw.y*ta[co+1][a1] + hw.z*ta[co+1][a2] + hw.w*ta[co+1][a3]; \
        o.z = hw.x*ta[co+2][a0] + hw.y*ta[co+2][a1] + hw.z*ta[co+2][a2] + hw.w*ta[co+2][a3]; \
        o.w = hw.x*ta[co+3][a0] + hw.y*ta[co+3][a1] + hw.z*ta[co+3][a2] + hw.w*ta[co+3][a3]; \
        __builtin_nontemporal_store(o, (nfloat4*)(obase + (size_t)r * TGT + W0 + co)); \
      }

    if (c >= 2 && c <= 40) {
      VROWS(0, 0, 1, 2, 3)
      VROWS(7, 1, 2, 3, 4)
    } else if (c == 0) {
      VROWS(0, 0, 0, 0, 1)
      VROWS(7, 0, 0, 1, 2)
    } else if (c == 1) {
      VROWS(0, 0, 0, 1, 2)
      VROWS(7, 0, 1, 2, 3)
    } else if (c == 41) {
      VROWS(0, 0, 1, 2, 3)
      VROWS(7, 1, 2, 3, 3)
    } else {
      VROWS(0, 0, 1, 2, 2)
      VROWS(7, 1, 2, 2, 2)
    }
    #undef VROWS
  } else if (t < 152) {
    // tail pair threads: t=150 -> cols (600,601) on even rows;
    //                    t=151 -> cols (0,1)     on odd rows.
    int W0 = (t == 150) ? 600 : 0;
    int par = (t == 150) ? 0 : 1;
    int m0 = W0 / 14;
    int j0 = W0 - m0 * 14;           // 12 or 0 -> pair never crosses 6->7
    int wb0 = m0 - 2 + (j0 >= 7);
    float4 w0 = wq[j0], w1 = wq[j0 + 1];

    int i0 = min(P - 1, max(0, wb0));
    int i1 = min(P - 1, max(0, wb0 + 1));
    int i2 = min(P - 1, max(0, wb0 + 2));
    int i3 = min(P - 1, max(0, wb0 + 3));

    float ta[5], tb[5];
    #pragma unroll
    for (int h = 0; h < 5; ++h) {
      const float* rowp = img + h * P;
      float v0 = rowp[i0], v1 = rowp[i1], v2 = rowp[i2], v3 = rowp[i3];
      ta[h] = w0.x * v0 + w0.y * v1 + w0.z * v2 + w0.w * v3;
      tb[h] = w1.x * v0 + w1.y * v1 + w1.z * v2 + w1.w * v3;
    }

    #define TROWS(R0, a0, a1, a2, a3)                                          \
      _Pragma("unroll")                                                        \
      for (int r = R0; r < R0 + 7; ++r) {                                      \
        if ((r & 1) == par) {                                                  \
          float4 hw = wq[r];                                                   \
          float ox = hw.x*ta[a0] + hw.y*ta[a1] + hw.z*ta[a2] + hw.w*ta[a3];    \
          float oy = hw.x*tb[a0] + hw.y*tb[a1] + hw.z*tb[a2] + hw.w*tb[a3];    \
          *(float2*)(obase + (size_t)r * TGT + W0) = make_float2(ox, oy);      \
        }                                                                      \
      }

    if (c >= 2 && c <= 40) {
      TROWS(0, 0, 1, 2, 3)
      TROWS(7, 1, 2, 3, 4)
    } else if (c == 0) {
      TROWS(0, 0, 0, 0, 1)
      TROWS(7, 0, 0, 1, 2)
    } else if (c == 1) {
      TROWS(0, 0, 0, 1, 2)
      TROWS(7, 0, 1, 2, 3)
    } else if (c == 41) {
      TROWS(0, 0, 1, 2, 3)
      TROWS(7, 1, 2, 3, 3)
    } else {
      TROWS(0, 0, 1, 2, 2)
      TROWS(7, 1, 2, 2, 2)
    }
    #undef TROWS
  }
}

// ---------------- launch ------------------------------------------------------
extern "C" void kernel_launch(void* const* d_in, const int* in_sizes, int n_in,
                              void* d_out, int out_size, void* d_ws, size_t ws_size,
                              hipStream_t stream) {
  const float* feats = (const float*)d_in[0];
  const float* emb   = (const float*)d_in[1];
  float* out = (float*)d_out;
  char* ws = (char*)d_ws;

  auto align64 = [](size_t x) { return (x + 63) & ~(size_t)63; };
  size_t off = 0;
  float* cosim  = (float*)(ws + off); off = align64(off + PLANE * 4);
  float* e_norm = (float*)(ws + off); off = align64(off + NEMB * 4);
  float4* gtw   = (float4*)(ws + off); off = align64(off + 14 * 16);
  float* fpart  = (float*)(ws + off); off = align64(off + (size_t)SPLIT * ROWS * 4);
  float* part   = (float*)(ws + off); off = align64(off + (size_t)SPLIT * PLANE * 4);

  prep_kernel<<<dim3(NEMB + 1), dim3(256), 0, stream>>>(emb, e_norm, gtw);
  gemm_partial<<<dim3((ROWS + BM - 1) / BM, SPLIT), dim3(256), 0, stream>>>(
      feats, emb, part, fpart);
  reduce_kernel<<<dim3((int)((PLANE + 255) / 256)), dim3(256), 0, stream>>>(
      part, fpart, e_norm, cosim);
  resize_kernel<<<dim3(43, 320), dim3(192), 0, stream>>>(cosim, gtw, out);
}

// Round 14
// 179.355 us; speedup vs baseline: 1.1360x; 1.1360x over previous
//
#include <hip/hip_runtime.h>
#include <math.h>

#define EPS 1e-8f
constexpr int D     = 1024;
constexpr int NEMB  = 80;
constexpr int K     = 1849;
constexpr int BATCH = 4;
constexpr int P     = 43;
constexpr int TGT   = 602;
constexpr int ROWS  = BATCH * K;                   // 7396
constexpr size_t PLANE = (size_t)BATCH * NEMB * K; // 591,680
constexpr int SPLIT = 8;
constexpr int KC    = D / SPLIT;                   // 128

typedef float nfloat4 __attribute__((ext_vector_type(4)));

// ---------------- bicubic tap weights (exact fp64, matches numpy) -----------
__device__ inline double cubic_w(double x) {
  const double A = -0.75;
  x = fabs(x);
  if (x <= 1.0) return ((A + 2.0) * x - (A + 3.0)) * x * x + 1.0;
  if (x < 2.0)  return A * (((x - 5.0) * x + 8.0) * x - 4.0);
  return 0.0;
}

__device__ inline float block_reduce_sum256(float v) {
  #pragma unroll
  for (int off = 32; off > 0; off >>= 1) v += __shfl_down(v, off, 64);
  __shared__ float red[4];
  int lane = threadIdx.x & 63, wid = threadIdx.x >> 6;
  if (lane == 0) red[wid] = v;
  __syncthreads();
  float r = 0.f;
  if (threadIdx.x == 0) r = red[0] + red[1] + red[2] + red[3];
  return r;
}

// blocks 0..79: e_norm rows; block 80: the 14-entry periodic weight table.
__global__ __launch_bounds__(256) void prep_kernel(
    const float* __restrict__ emb, float* __restrict__ e_norm,
    float4* __restrict__ gtw) {
  int bid = blockIdx.x;
  if (bid < NEMB) {
    float4 v = ((const float4*)(emb + (size_t)bid * D))[threadIdx.x];
    float s = v.x * v.x + v.y * v.y + v.z * v.z + v.w * v.w;
    s = block_reduce_sum256(s);
    if (threadIdx.x == 0) e_norm[bid] = sqrtf(s);
  } else {
    int j = threadIdx.x;
    if (j < 14) {
      double scale = (double)P / (double)TGT;
      double src = ((double)j + 0.5) * scale - 0.5;
      double fb = floor(src);
      double t = src - fb;
      float4 w;
      w.x = (float)cubic_w(t + 1.0);
      w.y = (float)cubic_w(t);
      w.z = (float)cubic_w(t - 1.0);
      w.w = (float)cubic_w(t - 2.0);
      gtw[j] = w;
    }
  }
}

// -------- split-K GEMM, 2-phase pipelined (R6 verbatim, SPLIT=8) -------------
constexpr int BM  = 64;
constexpr int BK  = 32;
constexpr int LDA = 36; // padded LDS row stride (floats), 16B aligned
constexpr int NT  = KC / BK; // 4 K-tiles per block

__device__ inline float dot4(float4 v) {
  return v.x * v.x + v.y * v.y + v.z * v.z + v.w * v.w;
}

__global__ __launch_bounds__(256) void gemm_partial(
    const float* __restrict__ feats, const float* __restrict__ emb,
    float* __restrict__ part, float* __restrict__ fpart) {
  __shared__ float As[BM * LDA];
  __shared__ float Bs[NEMB * LDA];
  int t = threadIdx.x;
  int row0 = blockIdx.x * BM;
  int s = blockIdx.y;
  int tr = t >> 4, tc = t & 15;
  float acc[4][5] = {{0.f}};
  float ssq0 = 0.f, ssq1 = 0.f;

  int r = t >> 3, dg = t & 7;
  int gr0 = row0 + r, gr1 = row0 + 32 + r;
  bool ok0 = gr0 < ROWS, ok1 = gr1 < ROWS;
  const float* pA0 = feats + (size_t)gr0 * D + dg * 4;
  const float* pA1 = feats + (size_t)gr1 * D + dg * 4;
  const float* pB0 = emb + (size_t)r * D + dg * 4;
  const float* pB1 = emb + (size_t)(32 + r) * D + dg * 4;
  const float* pB2 = emb + (size_t)(64 + r) * D + dg * 4;
  bool okB2 = t < 128;

  int kbeg = s * KC;
  const float4 zero = make_float4(0.f, 0.f, 0.f, 0.f);
  float4 a0 = ok0 ? *(const float4*)(pA0 + kbeg) : zero;
  float4 a1 = ok1 ? *(const float4*)(pA1 + kbeg) : zero;
  float4 b0 = *(const float4*)(pB0 + kbeg);
  float4 b1 = *(const float4*)(pB1 + kbeg);
  float4 b2 = okB2 ? *(const float4*)(pB2 + kbeg) : zero;

  for (int tile = 0; tile < NT; ++tile) {
    ssq0 += dot4(a0);
    *(float4*)(As + r * LDA + dg * 4) = a0;
    ssq1 += dot4(a1);
    *(float4*)(As + (32 + r) * LDA + dg * 4) = a1;
    *(float4*)(Bs + r * LDA + dg * 4) = b0;
    *(float4*)(Bs + (32 + r) * LDA + dg * 4) = b1;
    if (okB2) *(float4*)(Bs + (64 + r) * LDA + dg * 4) = b2;
    __syncthreads();

    if (tile + 1 < NT) {
      int k1 = kbeg + (tile + 1) * BK;
      a0 = ok0 ? *(const float4*)(pA0 + k1) : zero;
      a1 = ok1 ? *(const float4*)(pA1 + k1) : zero;
      b0 = *(const float4*)(pB0 + k1);
      b1 = *(const float4*)(pB1 + k1);
      if (okB2) b2 = *(const float4*)(pB2 + k1);
    }

    #pragma unroll
    for (int dd = 0; dd < BK; dd += 4) {
      float4 a[4], b[5];
      #pragma unroll
      for (int j = 0; j < 4; ++j)  a[j]  = *(const float4*)(As + (tr * 4 + j) * LDA + dd);
      #pragma unroll
      for (int i2 = 0; i2 < 5; ++i2) b[i2] = *(const float4*)(Bs + (tc + i2 * 16) * LDA + dd);
      #pragma unroll
      for (int j = 0; j < 4; ++j)
        #pragma unroll
        for (int i2 = 0; i2 < 5; ++i2)
          acc[j][i2] += a[j].x * b[i2].x + a[j].y * b[i2].y +
                        a[j].z * b[i2].z + a[j].w * b[i2].w;
    }
    __syncthreads();
  }

  #pragma unroll
  for (int off = 4; off > 0; off >>= 1) {
    ssq0 += __shfl_down(ssq0, off, 8);
    ssq1 += __shfl_down(ssq1, off, 8);
  }
  if ((t & 7) == 0) {
    if (gr0 < ROWS) fpart[(size_t)s * ROWS + gr0] = ssq0;
    if (gr1 < ROWS) fpart[(size_t)s * ROWS + gr1] = ssq1;
  }

  float* pplane = part + (size_t)s * PLANE;
  #pragma unroll
  for (int j = 0; j < 4; ++j) {
    int gr = row0 + tr * 4 + j;
    if (gr >= ROWS) continue;
    int b_ = gr / K;
    int k  = gr - b_ * K;
    #pragma unroll
    for (int i2 = 0; i2 < 5; ++i2) {
      int n = tc + i2 * 16;
      pplane[((size_t)(b_ * NEMB + n)) * K + k] = acc[j][i2];
    }
  }
}

// -------- reduce partials -> cosim (R6 verbatim, SPLIT=8) --------------------
__global__ __launch_bounds__(256) void reduce_kernel(
    const float* __restrict__ part, const float* __restrict__ fpart,
    const float* __restrict__ e_norm, float* __restrict__ cosim) {
  size_t e = (size_t)blockIdx.x * 256 + threadIdx.x;
  if (e >= PLANE) return;
  int bn = (int)(e / K);
  int k  = (int)(e - (size_t)bn * K);
  int b_ = bn / NEMB;
  int n  = bn - b_ * NEMB;
  int gr = b_ * K + k;
  float dot = 0.f, fn2 = 0.f;
  #pragma unroll
  for (int s = 0; s < SPLIT; ++s) {
    dot += part[(size_t)s * PLANE + e];
    fn2 += fpart[(size_t)s * ROWS + gr];
  }
  cosim[e] = dot / (sqrtf(fn2) * e_norm[n] + EPS);
}

// ---------------- separable bicubic resize: 7-row half-chunks ----------------
// grid (86, 320), 256 threads. Half-chunk hc=2c+h covers output rows
// 14c+7h .. 14c+7h+6, needing only 4 input rows (base=c-2+h..base+3, clamped).
// obuf 16.9 KB + img 0.7 KB -> 8 blocks/CU (32-wave cap): load+compute of ~8
// concurrent blocks hides under the BW-bound store drain. Store burst: 1053
// 16B NT stores (16B-aligned by parity offset) + one plain 8B head/tail.
__global__ __launch_bounds__(256) void resize_kernel(
    const float* __restrict__ cosim, const float4* __restrict__ gtw,
    float* __restrict__ out) {
  __shared__ float img[4 * P];        // 688 B
  __shared__ float4 wq[14];
  __shared__ float obuf[7 * TGT];     // 16,856 B packed

  int bn = blockIdx.y;
  int hc = blockIdx.x;
  int c  = hc >> 1, h = hc & 1;
  int t  = threadIdx.x;

  int base = c - 2 + h;               // first vertical tap row (unclamped)
  int hmin = max(0, base), hmax = min(P - 1, base + 3);
  int NH = hmax - hmin + 1;

  if (t < 14) wq[t] = gtw[t];
  const float* src = cosim + (size_t)bn * (P * P) + hmin * P;
  for (int i = t; i < NH * P; i += 256) img[i] = src[i];
  __syncthreads();

  for (int pw = t; pw < TGT / 2; pw += 256) {
    int W0 = pw * 2;
    int m0 = W0 / 14;
    int j0 = W0 - m0 * 14;
    int wb0 = m0 - 2 + (j0 >= 7);
    int j1 = (j0 == 13) ? 0 : j0 + 1;
    int d  = (j0 == 6) ? 1 : 0;
    float4 w0 = wq[j0], w1 = wq[j1];

    int i0 = min(P - 1, max(0, wb0));
    int i1 = min(P - 1, max(0, wb0 + 1));
    int i2 = min(P - 1, max(0, wb0 + 2));
    int i3 = min(P - 1, max(0, wb0 + 3));
    int i4 = min(P - 1, max(0, wb0 + 4));

    float ta[4], tb[4];
    #pragma unroll
    for (int hh = 0; hh < 4; ++hh) {
      const float* rowp = img + hh * P;
      float v0 = rowp[i0], v1 = rowp[i1], v2 = rowp[i2], v3 = rowp[i3], v4 = rowp[i4];
      ta[hh] = w0.x * v0 + w0.y * v1 + w0.z * v2 + w0.w * v3;
      float u0 = d ? v1 : v0;
      float u1 = d ? v2 : v1;
      float u2 = d ? v3 : v2;
      float u3 = d ? v4 : v3;
      tb[hh] = w1.x * u0 + w1.y * u1 + w1.z * u2 + w1.w * u3;
    }

    #define OUT7(A0, A1, A2, A3)                                             \
      _Pragma("unroll")                                                      \
      for (int r = 0; r < 7; ++r) {                                          \
        float4 hw = wq[r + 7 * h];                                           \
        float ox = hw.x*ta[A0] + hw.y*ta[A1] + hw.z*ta[A2] + hw.w*ta[A3];    \
        float oy = hw.x*tb[A0] + hw.y*tb[A1] + hw.z*tb[A2] + hw.w*tb[A3];    \
        *(float2*)(obuf + r * TGT + W0) = make_float2(ox, oy);               \
      }

    if (base >= 0 && base <= P - 4) { OUT7(0, 1, 2, 3) }      // interior
    else if (base == -2)            { OUT7(0, 0, 0, 1) }      // c=0,h=0
    else if (base == -1)            { OUT7(0, 0, 1, 2) }      // c=0,h=1 / c=1,h=0
    else if (base == P - 3)         { OUT7(0, 1, 2, 2) }      // base=40
    else                            { OUT7(0, 1, 1, 1) }      // base=41 (c=42,h=1)
    #undef OUT7
  }
  __syncthreads();

  // store burst: flat 4214 floats. h=0: 1053 x 16B NT + tail float2 @4212;
  // h=1: head float2 @0 + 1053 x 16B NT from float offset 2.
  // Alignment: gdst byte ≡ 8h (mod 16); +2h floats -> vec base ≡ 0 (mod 16).
  float* gdst = out + (size_t)bn * TGT * TGT + ((size_t)c * 14 + 7 * h) * TGT;
  int off0 = h ? 2 : 0;
  nfloat4* dvec = (nfloat4*)(gdst + off0);
  for (int i = t; i < 1053; i += 256) {
    float2 lo = *(const float2*)(obuf + off0 + i * 4);
    float2 hi = *(const float2*)(obuf + off0 + i * 4 + 2);
    nfloat4 v;
    v.x = lo.x; v.y = lo.y; v.z = hi.x; v.w = hi.y;
    __builtin_nontemporal_store(v, dvec + i);
  }
  if (t == 0) {
    int pos = h ? 0 : 4212;
    float2 tv = *(const float2*)(obuf + pos);
    *(float2*)(gdst + pos) = tv;    // plain 8B store (8B NT is broken; plain is safe)
  }
}

// ---------------- launch ------------------------------------------------------
extern "C" void kernel_launch(void* const* d_in, const int* in_sizes, int n_in,
                              void* d_out, int out_size, void* d_ws, size_t ws_size,
                              hipStream_t stream) {
  const float* feats = (const float*)d_in[0];
  const float* emb   = (const float*)d_in[1];
  float* out = (float*)d_out;
  char* ws = (char*)d_ws;

  auto align64 = [](size_t x) { return (x + 63) & ~(size_t)63; };
  size_t off = 0;
  float* cosim  = (float*)(ws + off); off = align64(off + PLANE * 4);
  float* e_norm = (float*)(ws + off); off = align64(off + NEMB * 4);
  float4* gtw   = (float4*)(ws + off); off = align64(off + 14 * 16);
  float* fpart  = (float*)(ws + off); off = align64(off + (size_t)SPLIT * ROWS * 4);
  float* part   = (float*)(ws + off); off = align64(off + (size_t)SPLIT * PLANE * 4);

  prep_kernel<<<dim3(NEMB + 1), dim3(256), 0, stream>>>(emb, e_norm, gtw);
  gemm_partial<<<dim3((ROWS + BM - 1) / BM, SPLIT), dim3(256), 0, stream>>>(
      feats, emb, part, fpart);
  reduce_kernel<<<dim3((int)((PLANE + 255) / 256)), dim3(256), 0, stream>>>(
      part, fpart, e_norm, cosim);
  resize_kernel<<<dim3(86, 320), dim3(256), 0, stream>>>(cosim, gtw, out);
}